// Round 6
// baseline (349.676 us; speedup 1.0000x reference)
//
#include <hip/hip_runtime.h>

#define B_  4
#define T_  2048
#define H_  16
#define DM_ 1024
#define DH_ 64
#define RK_ 32

using u16 = unsigned short;
using u32 = unsigned int;
typedef float  floatx4 __attribute__((ext_vector_type(4)));
typedef __bf16 bf16x8  __attribute__((ext_vector_type(8)));
typedef u16    u16x8   __attribute__((ext_vector_type(8)));
typedef u16    u16x4   __attribute__((ext_vector_type(4)));
typedef short  s16x4   __attribute__((ext_vector_type(4)));

#define MFMA16(a,b,c) __builtin_amdgcn_mfma_f32_16x16x32_bf16((a),(b),(c),0,0,0)
// K=16 bf16 MFMA: A/B frag = 4 bf16 (k = quad*4+j), C/D 16x16 layout
#define MFMA1K(a,b,c) __builtin_amdgcn_mfma_f32_16x16x16bf16_1k((a),(b),(c),0,0,0)

__device__ __forceinline__ u16 f2bf(float f) {
  unsigned u = __float_as_uint(f);
  u += 0x7fffu + ((u >> 16) & 1u);   // RNE
  return (u16)(u >> 16);
}
__device__ __forceinline__ float b2f(u16 h) {
  return __uint_as_float(((unsigned)h) << 16);
}
// RNE pack: (bf16(b)<<16)|bf16(a)
__device__ __forceinline__ u32 pack_bf(float a, float b) {
  u32 ua = __float_as_uint(a); ua += 0x7fffu + ((ua >> 16) & 1u);
  u32 ub = __float_as_uint(b); ub += 0x7fffu + ((ub >> 16) & 1u);
  return __builtin_amdgcn_perm(ub, ua, 0x07060302u);
}
// truncation pack (1 instr) — for P in the hot loop (values > 0)
__device__ __forceinline__ u32 tpack(float a, float b) {
  return __builtin_amdgcn_perm(__float_as_uint(b), __float_as_uint(a), 0x07060302u);
}

// async global->LDS, 16B per lane. LDS dest is wave-uniform base; HW adds lane*16.
__device__ __forceinline__ void async_copy16(const u16* g, const u16* lds_uniform_base) {
  __builtin_amdgcn_global_load_lds(
      (const __attribute__((address_space(1))) unsigned int*)(unsigned long long)g,
      (__attribute__((address_space(3))) unsigned int*)(unsigned int)(unsigned long long)lds_uniform_base,
      16, 0, 0);
}

// ---------------- conversion kernels ----------------
__global__ __launch_bounds__(256) void cvt_x(const float* __restrict__ s,
                                             u16* __restrict__ d, int n4) {
  int i = blockIdx.x * 256 + threadIdx.x;
  if (i >= n4) return;
  float4 v = reinterpret_cast<const float4*>(s)[i];
  u16x4 o = { f2bf(v.x), f2bf(v.y), f2bf(v.z), f2bf(v.w) };
  reinterpret_cast<u16x4*>(d)[i] = o;
}

__global__ __launch_bounds__(256) void cvt_weights(const float* __restrict__ Wq,
                                                   const float* __restrict__ Wk,
                                                   const float* __restrict__ Wv,
                                                   const float* __restrict__ Wo,
                                                   u16* __restrict__ Wcat) {
  int i = blockIdx.x * 256 + threadIdx.x;
  int reg = i >> 18;
  const float* s = (reg == 0) ? Wq : (reg == 1) ? Wk : (reg == 2) ? Wv : Wo;
  int j = i & 262143;
  float4 v = reinterpret_cast<const float4*>(s)[j];
  u16x4 o = { f2bf(v.x), f2bf(v.y), f2bf(v.z), f2bf(v.w) };
  reinterpret_cast<u16x4*>(Wcat)[i] = o;
}

// ---------------- GEMM: C[M,N] = A[M,K] * W[N,K]^T + bias, K=1024 ----------------
template <int OUTF32>
__global__ __launch_bounds__(256, 2) void gemm_bt(const u16* __restrict__ A,
                                                  const u16* __restrict__ W,
                                                  const float* __restrict__ b0,
                                                  const float* __restrict__ b1,
                                                  const float* __restrict__ b2,
                                                  void* __restrict__ Cv, int ldc) {
  __shared__ __align__(16) u16 Al[128 * 32];
  __shared__ __align__(16) u16 Bl[128 * 32];
  const int tid  = threadIdx.x;
  const int lane = tid & 63;
  const int wave = tid >> 6;
  const int quad = lane >> 4;
  const int l16  = lane & 15;
  const int wm   = (wave >> 1) << 6;
  const int wn   = (wave & 1) << 6;
  const int bm   = blockIdx.x * 128;
  const int bn   = blockIdx.y * 128;

  floatx4 acc[4][4];
#pragma unroll
  for (int i = 0; i < 4; i++)
#pragma unroll
    for (int j = 0; j < 4; j++) acc[i][j] = (floatx4){0.f, 0.f, 0.f, 0.f};

  const u16* Ag[2]; const u16* Wg[2]; u16* Alb[2]; u16* Blb[2];
#pragma unroll
  for (int issue = 0; issue < 2; issue++) {
    int c = issue * 256 + tid;
    Ag[issue]  = A + (size_t)(bm + (c >> 2)) * 1024 + (c & 3) * 8;
    Wg[issue]  = W + (size_t)(bn + (c >> 2)) * 1024 + (c & 3) * 8;
    int ub = (issue * 256 + wave * 64) * 8;
    Alb[issue] = Al + ub;
    Blb[issue] = Bl + ub;
  }

  for (int k0 = 0; k0 < 1024; k0 += 32) {
#pragma unroll
    for (int issue = 0; issue < 2; issue++) {
      async_copy16(Ag[issue] + k0, Alb[issue]);
      async_copy16(Wg[issue] + k0, Blb[issue]);
    }
    __syncthreads();
    bf16x8 af[4], bfr[4];
#pragma unroll
    for (int i = 0; i < 4; i++) {
      af[i]  = *reinterpret_cast<const bf16x8*>(Al + (wm + i * 16 + l16) * 32 + quad * 8);
      bfr[i] = *reinterpret_cast<const bf16x8*>(Bl + (wn + i * 16 + l16) * 32 + quad * 8);
    }
#pragma unroll
    for (int mi = 0; mi < 4; mi++)
#pragma unroll
      for (int ni = 0; ni < 4; ni++)
        acc[mi][ni] = MFMA16(af[mi], bfr[ni], acc[mi][ni]);
    __syncthreads();
  }

  const float* bp = (bn < 1024) ? b0 : ((bn < 2048) ? b1 : b2);
#pragma unroll
  for (int ni = 0; ni < 4; ni++) {
    int col = bn + wn + ni * 16 + l16;
    float bias = bp[col & 1023];
#pragma unroll
    for (int mi = 0; mi < 4; mi++)
#pragma unroll
      for (int r = 0; r < 4; r++) {
        int row = bm + wm + mi * 16 + quad * 4 + r;
        float v = acc[mi][ni][r] + bias;
        if (OUTF32)
          reinterpret_cast<float*>(Cv)[(size_t)row * ldc + col] = v;
        else
          reinterpret_cast<u16*>(Cv)[(size_t)row * ldc + col] = f2bf(v);
      }
  }
}

// ---------------- V transpose: vt[bh][d][t] ----------------
__global__ __launch_bounds__(256) void vtrans(const u16* __restrict__ qkv,
                                              u16* __restrict__ vt) {
  const int tb = blockIdx.x;
  const int bh = blockIdx.y;
  const int b = bh >> 4, h = bh & 15;
  __shared__ u16 Vl[64][72];
  const int tid = threadIdx.x;
#pragma unroll
  for (int it = 0; it < 2; it++) {
    int c = it * 256 + tid;
    int t = c >> 3, dc = (c & 7) * 8;
    u16x8 v = *reinterpret_cast<const u16x8*>(
        qkv + (size_t)(b * T_ + tb * 64 + t) * 3072 + 2048 + h * 64 + dc);
    *reinterpret_cast<u16x8*>(&Vl[t][dc]) = v;
  }
  __syncthreads();
#pragma unroll
  for (int it = 0; it < 2; it++) {
    int c = it * 256 + tid;
    int d = c >> 3, tt = (c & 7) * 8;
    u16x8 o;
#pragma unroll
    for (int j = 0; j < 8; j++) o[j] = Vl[tt + j][d];
    *reinterpret_cast<u16x8*>(vt + ((size_t)bh * 64 + d) * T_ + tb * 64 + tt) = o;
  }
}

// ---------------- LSR projection via MFMA ----------------
__global__ __launch_bounds__(256) void lsr_mfma(const u16* __restrict__ qkv,
                                                const float* __restrict__ Wql,
                                                const float* __restrict__ Wkl,
                                                u16* __restrict__ qlr,
                                                u16* __restrict__ klr) {
  const int t0 = blockIdx.x * 128;
  const int bh = blockIdx.y, b = bh >> 4, h = bh & 15;
  const int sel = blockIdx.z;
  const int tid = threadIdx.x, lane = tid & 63, w = tid >> 6;
  const int quad = lane >> 4, l16 = lane & 15;
  __shared__ __align__(16) u16 Al[128 * 64];
  __shared__ __align__(16) u16 Wl[32 * 72];

  const float* Wsrc = (sel ? Wkl : Wql) + h * 2048;
  const float fold = sel ? 1.0f : 0.25506100790944405f;  // (1/sqrt(32))*log2(e)
  {
    float4 a = *reinterpret_cast<const float4*>(Wsrc + tid * 8);
    float4 c = *reinterpret_cast<const float4*>(Wsrc + tid * 8 + 4);
    float vals[8] = {a.x, a.y, a.z, a.w, c.x, c.y, c.z, c.w};
#pragma unroll
    for (int i = 0; i < 8; i++) {
      int idx = tid * 8 + i, d = idx >> 5, r = idx & 31;
      Wl[r * 72 + d] = f2bf(vals[i] * fold);
    }
  }
#pragma unroll
  for (int issue = 0; issue < 4; issue++) {
    int l = issue * 256 + tid;
    int t = l >> 3, ck = l & 7;
    const u16* src = qkv + (size_t)(b * T_ + t0 + t) * 3072 + sel * 1024 + h * 64 +
                     ((ck ^ (t & 7)) * 8);
    async_copy16(src, Al + issue * 2048 + w * 512);
  }
  __syncthreads();

  bf16x8 wf[2][2], af[2][2];
#pragma unroll
  for (int mr = 0; mr < 2; mr++)
#pragma unroll
    for (int c = 0; c < 2; c++)
      wf[mr][c] = *reinterpret_cast<const bf16x8*>(&Wl[(mr * 16 + l16) * 72 + c * 32 + quad * 8]);
#pragma unroll
  for (int i = 0; i < 2; i++) {
    int t = (2 * w + i) * 16 + l16;
#pragma unroll
    for (int c = 0; c < 2; c++)
      af[i][c] = *reinterpret_cast<const bf16x8*>(&Al[t * 64 + (((4 * c + quad) ^ (t & 7)) * 8)]);
  }
  floatx4 acc[2][2];
#pragma unroll
  for (int i = 0; i < 2; i++)
#pragma unroll
    for (int mr = 0; mr < 2; mr++) acc[i][mr] = (floatx4){0.f, 0.f, 0.f, 0.f};
#pragma unroll
  for (int i = 0; i < 2; i++)
#pragma unroll
    for (int mr = 0; mr < 2; mr++)
#pragma unroll
      for (int c = 0; c < 2; c++)
        acc[i][mr] = MFMA16(wf[mr][c], af[i][c], acc[i][mr]);

  u16* outp = sel ? klr : qlr;
#pragma unroll
  for (int i = 0; i < 2; i++) {
    int t = t0 + (2 * w + i) * 16 + l16;
#pragma unroll
    for (int mr = 0; mr < 2; mr++) {
      uint2 pv = { pack_bf(acc[i][mr][0], acc[i][mr][1]),
                   pack_bf(acc[i][mr][2], acc[i][mr][3]) };
      *reinterpret_cast<uint2*>(outp + ((size_t)bh * T_ + t) * 32 + mr * 16 + quad * 4) = pv;
    }
  }
}

// ---------------- flash attention: one wave per (bh, q-tile-pair half) ----------------
// No LDS, no barriers. Wave = 64 threads handles 32 qrows (2 chunks of 16) of
// q-tile qi=31-j then qi=j (exactly 33 key-tiles — perfect balance; 2048 waves
// all co-resident). V/K fragments loaded straight from global (L2-resident;
// grid.x=bh gives XCD affinity). S^T = MFMA16(kf,qf); P stays in registers and
// feeds MFMA1K as B-operand; V^T is the A-operand loaded as dwordx2.
__global__ __launch_bounds__(64) void attn(const u16* __restrict__ qlr,
                                           const u16* __restrict__ klr,
                                           const u16* __restrict__ vt,
                                           u16* __restrict__ yatt) {
  const int bh = blockIdx.x;
  const int b = bh >> 4, h = bh & 15;
  const int j = blockIdx.y >> 1, half = blockIdx.y & 1;
  const int lane = threadIdx.x;
  const int quad = lane >> 4, l16 = lane & 15;

  const u16* qlr_bh = qlr + (size_t)bh * T_ * RK_;
  const u16* klr_l  = klr + (size_t)bh * T_ * RK_ + l16 * 32 + quad * 8;
  const u16* vt_l   = vt + (size_t)bh * 64 * T_ + (size_t)l16 * T_ + quad * 4;

  const int thr = half * 32 + l16;   // causal threshold for qc=0 rows (qc=1: +16)

#pragma unroll
  for (int seg = 0; seg < 2; seg++) {
    const int qi = seg ? j : 31 - j;
    const int q0 = qi * 64;

    bf16x8 qf0 = *reinterpret_cast<const bf16x8*>(
        qlr_bh + (size_t)(q0 + half * 32 + l16) * 32 + quad * 8);
    bf16x8 qf1 = *reinterpret_cast<const bf16x8*>(
        qlr_bh + (size_t)(q0 + half * 32 + 16 + l16) * 32 + quad * 8);

    const u16* kp = klr_l;
    bf16x8 kf[4];
#pragma unroll
    for (int nt = 0; nt < 4; nt++)
      kf[nt] = *reinterpret_cast<const bf16x8*>(kp + nt * 512);

    const u16* vp0 = vt_l;
    const u16* vp1 = vt_l + 16 * T_;
    const u16* vp2 = vt_l + 32 * T_;
    const u16* vp3 = vt_l + 48 * T_;

    floatx4 oacc[2][4];
#pragma unroll
    for (int qc = 0; qc < 2; qc++)
#pragma unroll
      for (int dt = 0; dt < 4; dt++) oacc[qc][dt] = (floatx4){0.f, 0.f, 0.f, 0.f};
    float rs0 = 0.f, rs1 = 0.f;
    const floatx4 fzero = {0.f, 0.f, 0.f, 0.f};

    for (int i = 0; i <= qi; i++) {
      // V fragments for this key-tile (A-operand: m=d, k=key quad*4..+3)
      s16x4 vf[4][4];
#pragma unroll
      for (int nt = 0; nt < 4; nt++) {
        vf[nt][0] = *reinterpret_cast<const s16x4*>(vp0 + nt * 16);
        vf[nt][1] = *reinterpret_cast<const s16x4*>(vp1 + nt * 16);
        vf[nt][2] = *reinterpret_cast<const s16x4*>(vp2 + nt * 16);
        vf[nt][3] = *reinterpret_cast<const s16x4*>(vp3 + nt * 16);
      }

      floatx4 sv0[4], sv1[4];
#pragma unroll
      for (int nt = 0; nt < 4; nt++) {
        sv0[nt] = MFMA16(kf[nt], qf0, fzero);
        sv1[nt] = MFMA16(kf[nt], qf1, fzero);
      }

      kp += 2048;
      if (i < qi) {
#pragma unroll
        for (int nt = 0; nt < 4; nt++)
          kf[nt] = *reinterpret_cast<const bf16x8*>(kp + nt * 512);
      }

      uint2 pk0[4], pk1[4];
      if (i != qi) {
#pragma unroll
        for (int nt = 0; nt < 4; nt++) {
          float a0 = __builtin_amdgcn_exp2f(sv0[nt][0]);
          float a1 = __builtin_amdgcn_exp2f(sv0[nt][1]);
          float a2 = __builtin_amdgcn_exp2f(sv0[nt][2]);
          float a3 = __builtin_amdgcn_exp2f(sv0[nt][3]);
          rs0 += (a0 + a1) + (a2 + a3);
          pk0[nt].x = tpack(a0, a1);
          pk0[nt].y = tpack(a2, a3);
          float c0 = __builtin_amdgcn_exp2f(sv1[nt][0]);
          float c1 = __builtin_amdgcn_exp2f(sv1[nt][1]);
          float c2 = __builtin_amdgcn_exp2f(sv1[nt][2]);
          float c3 = __builtin_amdgcn_exp2f(sv1[nt][3]);
          rs1 += (c0 + c1) + (c2 + c3);
          pk1[nt].x = tpack(c0, c1);
          pk1[nt].y = tpack(c2, c3);
        }
      } else {
#pragma unroll
        for (int nt = 0; nt < 4; nt++) {
          float a[4], c[4];
#pragma unroll
          for (int r = 0; r < 4; r++) {
            int key = nt * 16 + quad * 4 + r;
            a[r] = (key <= thr)      ? __builtin_amdgcn_exp2f(sv0[nt][r]) : 0.f;
            c[r] = (key <= thr + 16) ? __builtin_amdgcn_exp2f(sv1[nt][r]) : 0.f;
          }
          rs0 += (a[0] + a[1]) + (a[2] + a[3]);
          rs1 += (c[0] + c[1]) + (c[2] + c[3]);
          pk0[nt].x = tpack(a[0], a[1]);
          pk0[nt].y = tpack(a[2], a[3]);
          pk1[nt].x = tpack(c[0], c[1]);
          pk1[nt].y = tpack(c[2], c[3]);
        }
      }

#pragma unroll
      for (int dt = 0; dt < 4; dt++)
#pragma unroll
        for (int nt = 0; nt < 4; nt++) {
          oacc[0][dt] = MFMA1K(vf[nt][dt], __builtin_bit_cast(s16x4, pk0[nt]), oacc[0][dt]);
          oacc[1][dt] = MFMA1K(vf[nt][dt], __builtin_bit_cast(s16x4, pk1[nt]), oacc[1][dt]);
        }

      vp0 += 64; vp1 += 64; vp2 += 64; vp3 += 64;
    }

    // row-sums span the 4 quads (lanes l16, +16, +32, +48)
    rs0 += __shfl_xor(rs0, 16);
    rs0 += __shfl_xor(rs0, 32);
    rs1 += __shfl_xor(rs1, 16);
    rs1 += __shfl_xor(rs1, 32);
    float inv0 = 1.f / rs0, inv1 = 1.f / rs1;

    const int qrow0 = q0 + half * 32 + l16;
#pragma unroll
    for (int dt = 0; dt < 4; dt++) {
      uint2 o0 = { pack_bf(oacc[0][dt][0] * inv0, oacc[0][dt][1] * inv0),
                   pack_bf(oacc[0][dt][2] * inv0, oacc[0][dt][3] * inv0) };
      *reinterpret_cast<uint2*>(
          yatt + (size_t)(b * T_ + qrow0) * 1024 + h * 64 + dt * 16 + quad * 4) = o0;
      uint2 o1 = { pack_bf(oacc[1][dt][0] * inv1, oacc[1][dt][1] * inv1),
                   pack_bf(oacc[1][dt][2] * inv1, oacc[1][dt][3] * inv1) };
      *reinterpret_cast<uint2*>(
          yatt + (size_t)(b * T_ + qrow0 + 16) * 1024 + h * 64 + dt * 16 + quad * 4) = o1;
    }
  }
}

// ---------------- launch ----------------
extern "C" void kernel_launch(void* const* d_in, const int* in_sizes, int n_in,
                              void* d_out, int out_size, void* d_ws, size_t ws_size,
                              hipStream_t stream) {
  const float* x   = (const float*)d_in[0];
  const float* Wq  = (const float*)d_in[1];
  const float* bq  = (const float*)d_in[2];
  const float* Wk  = (const float*)d_in[3];
  const float* bk  = (const float*)d_in[4];
  const float* Wv  = (const float*)d_in[5];
  const float* bv  = (const float*)d_in[6];
  const float* Wo  = (const float*)d_in[7];
  const float* bo  = (const float*)d_in[8];
  const float* Wql = (const float*)d_in[9];
  const float* Wkl = (const float*)d_in[10];
  float* out = (float*)d_out;

  char* ws = (char*)d_ws;
  u16* xb   = (u16*)(ws);                    // 8192x1024 bf16 (16 MB) -- reused as vt
  u16* Wcat = (u16*)(ws + 16777216);         // 4096x1024 bf16 (8 MB)
  u16* qkv  = (u16*)(ws + 25165824);         // 8192x3072 bf16 (50 MB)
  u16* qlr  = (u16*)(ws + 75497472);         // 64x2048x32 bf16 (8 MB)
  u16* klr  = (u16*)(ws + 83886080);         // 64x2048x32 bf16 (8 MB)
  u16* yatt = (u16*)(ws + 92274688);         // 8192x1024 bf16 (16 MB)
  u16* vt   = xb;                            // [bh][64][2048] bf16, after gemm0

  cvt_x<<<dim3(8192), 256, 0, stream>>>(x, xb, 2097152);
  cvt_weights<<<dim3(4096), 256, 0, stream>>>(Wq, Wk, Wv, Wo, Wcat);
  gemm_bt<0><<<dim3(64, 24), 256, 0, stream>>>(xb, Wcat, bq, bk, bv, qkv, 3072);
  vtrans<<<dim3(32, 64), 256, 0, stream>>>(qkv, vt);
  lsr_mfma<<<dim3(16, 64, 2), 256, 0, stream>>>(qkv, Wql, Wkl, qlr, klr);
  attn<<<dim3(64, 32), 64, 0, stream>>>(qlr, klr, vt, yatt);
  gemm_bt<1><<<dim3(64, 8), 256, 0, stream>>>(yatt, Wcat + 3145728, bo, bo, bo, out, 1024);
}